// Round 11
// baseline (98.801 us; speedup 1.0000x reference)
//
#include <hip/hip_runtime.h>
#include <math.h>

#define Bsz 8
#define Kc 4
#define Nn 16
#define Ss 64
#define Hh 512
#define F2 1024   // 2H = per-part K dim

__device__ __forceinline__ float logsigf(float x) {
    return fminf(x, 0.0f) - log1pf(expf(-fabsf(x)));
}

// ---- DPP wave64 inclusive scans ----
template<int Ctrl, int RowMask>
__device__ __forceinline__ float dpp_add(float x) {
    int v = __builtin_amdgcn_update_dpp(0, __float_as_int(x), Ctrl, RowMask, 0xf, false);
    return x + __int_as_float(v);
}
template<int Ctrl, int RowMask>
__device__ __forceinline__ float dpp_max(float x) {
    int v = __builtin_amdgcn_update_dpp(__float_as_int(-INFINITY), __float_as_int(x),
                                        Ctrl, RowMask, 0xf, false);
    return fmaxf(x, __int_as_float(v));
}
__device__ __forceinline__ float wave_scan_add(float x) {
    x = dpp_add<0x111, 0xf>(x); x = dpp_add<0x112, 0xf>(x);
    x = dpp_add<0x114, 0xf>(x); x = dpp_add<0x118, 0xf>(x);
    x = dpp_add<0x142, 0xa>(x); x = dpp_add<0x143, 0xc>(x);
    return x;
}
__device__ __forceinline__ float wave_scan_max(float x) {
    x = dpp_max<0x111, 0xf>(x); x = dpp_max<0x112, 0xf>(x);
    x = dpp_max<0x114, 0xf>(x); x = dpp_max<0x118, 0xf>(x);
    x = dpp_max<0x142, 0xa>(x); x = dpp_max<0x143, 0xc>(x);
    return x;
}

// ---------------- K1: GEMM, K-quarters in-block, 4x4 microtile ----------------
// grid (8,16,2): tile 64m x 32n.  z=0: T = seg @ W1[:1024]; z=1: V = vid @ W1[1024:].
// 512 thr = 4 K-quarters x 128 thr.  Quarter q covers K[256q, 256q+256), 8 steps
// of BK=32, double-buffered.  Microtile 4m x 4n (16 FMA / 32B LDS — balanced).
// Epilogue: quarters 1-3 dump acc to LDS, quarter 0 reduces and writes.
__global__ __launch_bounds__(512) void gemm_kernel(
    const float* __restrict__ seg, const float* __restrict__ vid,
    const float* __restrict__ W1,
    float* __restrict__ Tfin, float* __restrict__ Vfin)
{
    const int z = blockIdx.z;
    const float* __restrict__ Amat = z ? vid : seg;
    const float* __restrict__ Bmat = W1 + (z ? (size_t)F2 * Hh : 0);
    float* __restrict__ Out = z ? Vfin : Tfin;
    const int r0 = blockIdx.x * 64;
    const int n0 = blockIdx.y * 32;
    const int t = threadIdx.x;
    const int q   = t >> 7;        // K-quarter 0..3
    const int qt  = t & 127;

    __shared__ __align__(16) float As[4][2][32][68];  // [q][buf][k][m] transposed
    __shared__ __align__(16) float Bs[4][2][32][36];  // [q][buf][k][n]

    const int mt = (qt >> 3) << 2;      // 0..60
    const int nt = (qt & 7) << 2;       // 0..28
    const int ari = qt >> 1;            // A row 0..63
    const int aq0 = (qt & 1) << 2;      // A quad base 0 or 4
    const int brk = qt >> 2;            // B k-row 0..31
    const int bcb = (qt & 3) << 3;      // B col base 0,8,16,24

    float4 ra0, ra1, ra2, ra3, rb0, rb1;
    auto load_step = [&](int s) {
        const int k0 = q * 256 + s * 32;
        const float* arow = Amat + (size_t)(r0 + ari) * F2 + k0;
        ra0 = *reinterpret_cast<const float4*>(arow + 4 * (aq0 + 0));
        ra1 = *reinterpret_cast<const float4*>(arow + 4 * (aq0 + 1));
        ra2 = *reinterpret_cast<const float4*>(arow + 4 * (aq0 + 2));
        ra3 = *reinterpret_cast<const float4*>(arow + 4 * (aq0 + 3));
        const float* brow = Bmat + (size_t)(k0 + brk) * Hh + n0 + bcb;
        rb0 = *reinterpret_cast<const float4*>(brow);
        rb1 = *reinterpret_cast<const float4*>(brow + 4);
    };
    auto write_step = [&](int buf) {
        As[q][buf][4*(aq0+0)+0][ari] = ra0.x; As[q][buf][4*(aq0+0)+1][ari] = ra0.y;
        As[q][buf][4*(aq0+0)+2][ari] = ra0.z; As[q][buf][4*(aq0+0)+3][ari] = ra0.w;
        As[q][buf][4*(aq0+1)+0][ari] = ra1.x; As[q][buf][4*(aq0+1)+1][ari] = ra1.y;
        As[q][buf][4*(aq0+1)+2][ari] = ra1.z; As[q][buf][4*(aq0+1)+3][ari] = ra1.w;
        As[q][buf][4*(aq0+2)+0][ari] = ra2.x; As[q][buf][4*(aq0+2)+1][ari] = ra2.y;
        As[q][buf][4*(aq0+2)+2][ari] = ra2.z; As[q][buf][4*(aq0+2)+3][ari] = ra2.w;
        As[q][buf][4*(aq0+3)+0][ari] = ra3.x; As[q][buf][4*(aq0+3)+1][ari] = ra3.y;
        As[q][buf][4*(aq0+3)+2][ari] = ra3.z; As[q][buf][4*(aq0+3)+3][ari] = ra3.w;
        *reinterpret_cast<float4*>(&Bs[q][buf][brk][bcb])     = rb0;
        *reinterpret_cast<float4*>(&Bs[q][buf][brk][bcb + 4]) = rb1;
    };

    float acc[4][4] = {{0.f}};
    auto compute = [&](int cur) {
        #pragma unroll
        for (int kk = 0; kk < 32; ++kk) {
            float4 a4 = *reinterpret_cast<const float4*>(&As[q][cur][kk][mt]);
            float4 b4 = *reinterpret_cast<const float4*>(&Bs[q][cur][kk][nt]);
            float av[4] = {a4.x, a4.y, a4.z, a4.w};
            float bv[4] = {b4.x, b4.y, b4.z, b4.w};
            #pragma unroll
            for (int i = 0; i < 4; ++i)
                #pragma unroll
                for (int j = 0; j < 4; ++j)
                    acc[i][j] = fmaf(av[i], bv[j], acc[i][j]);
        }
    };

    load_step(0);
    write_step(0);
    __syncthreads();
    #pragma unroll 1
    for (int s = 0; s < 8; ++s) {
        const int cur = s & 1;
        if (s + 1 < 8) load_step(s + 1);
        compute(cur);
        if (s + 1 < 8) {
            write_step(cur ^ 1);
            __syncthreads();
        }
    }
    __syncthreads();
    // ---- cross-quarter reduction ----
    float* red = &As[0][0][0][0];   // 24 KB needed, 69 KB available
    if (q >= 1) {
        #pragma unroll
        for (int i = 0; i < 4; ++i)
            *reinterpret_cast<float4*>(&red[(((q - 1) * 128 + qt) * 16) + 4 * i]) =
                make_float4(acc[i][0], acc[i][1], acc[i][2], acc[i][3]);
    }
    __syncthreads();
    if (q == 0) {
        #pragma unroll
        for (int i = 0; i < 4; ++i) {
            float4 o = make_float4(acc[i][0], acc[i][1], acc[i][2], acc[i][3]);
            #pragma unroll
            for (int p = 0; p < 3; ++p) {
                float4 v = *reinterpret_cast<const float4*>(
                    &red[((p * 128 + qt) * 16) + 4 * i]);
                o.x += v.x; o.y += v.y; o.z += v.z; o.w += v.w;
            }
            *reinterpret_cast<float4*>(Out + (size_t)(r0 + mt + i) * Hh + n0 + nt) = o;
        }
    }
}

// ---------------- K2: combine, 512 blocks (2/CU): logits = w2.relu(T+V+b1)+b2 ----
// bid = b*64 + sc*8 + rq.  Block: 8 kn-rows (rq) x 8 s (sc).  Wave w: 2 kn.
__global__ __launch_bounds__(256) void combine_kernel(
    const float* __restrict__ Tfin, const float* __restrict__ Vfin,
    const float* __restrict__ b1, const float* __restrict__ w2,
    const float* __restrict__ b2, float* __restrict__ logits)
{
    const int bid = blockIdx.x;
    const int b  = bid >> 6;
    const int sc = (bid >> 3) & 7;
    const int rq = bid & 7;
    const int t = threadIdx.x;
    const int wave = t >> 6, lane = t & 63;
    __shared__ float Vs[8][516];
    {
        const int row = t >> 5;              // 0..7
        const int f0  = t & 31;              // f4 index base
        const float* src = Vfin + (size_t)(b * Ss + sc * 8 + row) * Hh;
        #pragma unroll
        for (int j = 0; j < 4; ++j)
            *reinterpret_cast<float4*>(&Vs[row][(f0 + 32 * j) * 4]) =
                *reinterpret_cast<const float4*>(src + (f0 + 32 * j) * 4);
    }
    float w2r[8], b1r[8];
    #pragma unroll
    for (int j = 0; j < 8; ++j) { w2r[j] = w2[lane + 64 * j]; b1r[j] = b1[lane + 64 * j]; }
    const float bias2 = b2[0];
    // 2 T-rows in registers
    float tj0[8], tj1[8];
    {
        const int r0i = b * 64 + rq * 8 + wave * 2;
        const float* t0 = Tfin + (size_t)r0i * Hh;
        const float* t1 = t0 + Hh;
        #pragma unroll
        for (int j = 0; j < 8; ++j) {
            tj0[j] = t0[lane + 64 * j] + b1r[j];
            tj1[j] = t1[lane + 64 * j] + b1r[j];
        }
    }
    __syncthreads();
    const int rbase = b * 64 + rq * 8 + wave * 2;
    #pragma unroll
    for (int si = 0; si < 8; ++si) {
        float s0 = 0.f, s1 = 0.f;
        #pragma unroll
        for (int j = 0; j < 8; ++j) {
            const float v = Vs[si][lane + 64 * j];
            s0 = fmaf(fmaxf(tj0[j] + v, 0.f), w2r[j], s0);
            s1 = fmaf(fmaxf(tj1[j] + v, 0.f), w2r[j], s1);
        }
        s0 = wave_scan_add(s0);
        s1 = wave_scan_add(s1);
        if (lane == 63) {
            logits[(size_t)rbase * Ss + sc * 8 + si]       = s0 + bias2;
            logits[(size_t)(rbase + 1) * Ss + sc * 8 + si] = s1 + bias2;
        }
    }
}

// ---------------- K3: DP via DPP prefix-max (R6, validated) ----------------
__global__ __launch_bounds__(256) void dp_kernel(
    const float* __restrict__ logits, const float* __restrict__ labels,
    float* __restrict__ out)
{
    const int b = blockIdx.x;
    const int t = threadIdx.x;
    const int k = t >> 6, rl = t & 63;
    const int sI = 63 - rl;
    __shared__ float lgs[Kc][Nn][Ss];
    __shared__ unsigned long long ch[Kc][Nn];
    __shared__ float bestS[Kc], aggS[Kc];
    __shared__ int alS[Kc][Nn];
    const float* lg = logits + (size_t)((b * Kc + k) * Nn) * Ss;
    float lv[Nn];
    #pragma unroll
    for (int n = 0; n < Nn; ++n) {
        lv[n] = lg[n * Ss + sI];
        lgs[k][n][sI] = lv[n];
    }
    float arr = -100.0f;
    #pragma unroll
    for (int n = Nn - 1; n >= 0; --n) {
        const float L = logsigf(lv[n]);
        const float c = (n == Nn - 1) ? L : (L + arr);
        const bool in_band = (rl <= 63 - n) && (rl >= 15 - n);   // s in [n, 48+n]
        float m = in_band ? c : -INFINITY;
        m = wave_scan_max(m);
        const float row = in_band ? fmaxf(m, -100.0f) : -100.0f;
        float rnA = __int_as_float(__builtin_amdgcn_update_dpp(
            __float_as_int(-1e30f), __float_as_int(row), 0x111, 0xf, 0xf, false));
        float b15 = __int_as_float(__builtin_amdgcn_update_dpp(
            0, __float_as_int(row), 0x142, 0xa, 0xf, false));
        float b31 = __int_as_float(__builtin_amdgcn_update_dpp(
            0, __float_as_int(row), 0x143, 0xc, 0xf, false));
        float rn = ((rl & 15) == 0 && rl != 0) ? ((rl == 32) ? b31 : b15) : rnA;
        unsigned long long mask = __ballot(in_band && (c >= rn));
        if (rl == 0) ch[k][n] = __brevll(mask);
        arr = row;
    }
    const float best = __shfl(arr, 63);
    __syncthreads();
    if (rl == 0) {
        float agg = 0.f;
        int start = 0;
        bool dead = false;
        int alignv[Nn];
        #pragma unroll
        for (int n = 0; n < Nn; ++n) {
            unsigned long long m2 = dead ? 0ull : (ch[k][n] & (~0ull << start));
            if (m2) {
                const int s = __builtin_ctzll(m2);
                agg += lgs[k][n][s];
                alignv[n] = s;
                start = s + 1;
            } else {
                alignv[n] = 0;
                dead = true;
            }
        }
        bestS[k] = best; aggS[k] = agg;
        #pragma unroll
        for (int n = 0; n < Nn; ++n) alS[k][n] = alignv[n];
    }
    __syncthreads();
    if (t == 0) {
        int kb = 0; float bb = bestS[0];
        #pragma unroll
        for (int kk = 1; kk < Kc; ++kk)
            if (bestS[kk] > bb) { bb = bestS[kk]; kb = kk; }
        out[b] = 1.0f / (1.0f + expf(-aggS[kb]));
        out[Bsz + b] = labels[b];
        #pragma unroll
        for (int n = 0; n < Nn; ++n)
            out[2 * Bsz + b * Nn + n] = (float)alS[kb][n];
    }
}

extern "C" void kernel_launch(void* const* d_in, const int* in_sizes, int n_in,
                              void* d_out, int out_size, void* d_ws, size_t ws_size,
                              hipStream_t stream) {
    const float* seg    = (const float*)d_in[0];
    const float* vid    = (const float*)d_in[1];
    const float* labels = (const float*)d_in[2];
    const float* W1     = (const float*)d_in[3];
    const float* b1     = (const float*)d_in[4];
    const float* w2     = (const float*)d_in[5];
    const float* b2     = (const float*)d_in[6];
    float* out = (float*)d_out;

    float* Tfin   = (float*)d_ws;
    float* Vfin   = Tfin + (size_t)512 * Hh;
    float* logits = Vfin + (size_t)512 * Hh;

    hipLaunchKernelGGL(gemm_kernel, dim3(8, 16, 2), dim3(512), 0, stream,
                       seg, vid, W1, Tfin, Vfin);
    hipLaunchKernelGGL(combine_kernel, dim3(512), dim3(256), 0, stream,
                       Tfin, Vfin, b1, w2, b2, logits);
    hipLaunchKernelGGL(dp_kernel, dim3(Bsz), dim3(256), 0, stream, logits, labels, out);
}

// Round 12
// 52.938 us; speedup vs baseline: 1.8663x; 1.8663x over previous
//
#include <hip/hip_runtime.h>
#include <math.h>

#define Bsz 8
#define Kc 4
#define Nn 16
#define Ss 64
#define Hh 512
#define F2 1024   // 2H = per-part K dim

__device__ __forceinline__ float logsigf(float x) {
    return fminf(x, 0.0f) - log1pf(expf(-fabsf(x)));
}

// ---- DPP wave64 inclusive scans ----
template<int Ctrl, int RowMask>
__device__ __forceinline__ float dpp_add(float x) {
    int v = __builtin_amdgcn_update_dpp(0, __float_as_int(x), Ctrl, RowMask, 0xf, false);
    return x + __int_as_float(v);
}
template<int Ctrl, int RowMask>
__device__ __forceinline__ float dpp_max(float x) {
    int v = __builtin_amdgcn_update_dpp(__float_as_int(-INFINITY), __float_as_int(x),
                                        Ctrl, RowMask, 0xf, false);
    return fmaxf(x, __int_as_float(v));
}
__device__ __forceinline__ float wave_scan_add(float x) {
    x = dpp_add<0x111, 0xf>(x); x = dpp_add<0x112, 0xf>(x);
    x = dpp_add<0x114, 0xf>(x); x = dpp_add<0x118, 0xf>(x);
    x = dpp_add<0x142, 0xa>(x); x = dpp_add<0x143, 0xc>(x);
    return x;
}
__device__ __forceinline__ float wave_scan_max(float x) {
    x = dpp_max<0x111, 0xf>(x); x = dpp_max<0x112, 0xf>(x);
    x = dpp_max<0x114, 0xf>(x); x = dpp_max<0x118, 0xf>(x);
    x = dpp_max<0x142, 0xa>(x); x = dpp_max<0x143, 0xc>(x);
    return x;
}

// ---------------- K1: GEMM — XCD-clustered, barrier-free per-wave split-K ----------
// grid 256 (1-D).  xcd = lin&7 (round-robin XCD): z = xcd>>2, xx = (xcd&3)*2+(idx&1),
// yy = idx>>1  -> per-XCD working set = 2 A-tiles (512 KB) + one z's W1 (2 MB) < 4 MB L2.
// 512 thr = 8 waves; wave w owns K[w*128, w*128+128), 8 steps of BK=16,
// PRIVATE double-buffered LDS staging (no __syncthreads in main loop),
// register prefetch 2 tiles ahead.  Microtile 8m x 4n.  Epilogue: one barrier,
// 8-way cross-wave sum through reused LDS, coalesced float4 stores.
__global__ __launch_bounds__(512) void gemm_kernel(
    const float* __restrict__ seg, const float* __restrict__ vid,
    const float* __restrict__ W1,
    float* __restrict__ Tfin, float* __restrict__ Vfin)
{
    const int lin = blockIdx.x;
    const int xcd = lin & 7;
    const int idx = lin >> 3;
    const int z   = xcd >> 2;
    const int xx  = (xcd & 3) * 2 + (idx & 1);
    const int yy  = idx >> 1;
    const float* __restrict__ Amat = z ? vid : seg;
    const float* __restrict__ Bmat = W1 + (z ? (size_t)F2 * Hh : 0);
    float* __restrict__ Out = z ? Vfin : Tfin;
    const int r0 = xx * 64;
    const int n0 = yy * 32;

    const int t = threadIdx.x;
    const int w = t >> 6;
    const int l = t & 63;
    const int kbase = w << 7;           // w*128

    // smem carve: As(w): [2 buf][16 kk][68 m-pad] at w*2176; Bs(w): [2][16][36] at 17408+w*1152
    // epilogue red: 8 x 2304 floats (lane-stride 36) fits in the same 26624-float block.
    __shared__ __align__(16) float smem[26624];
    float* As_w = smem + w * 2176;
    float* Bs_w = smem + 17408 + w * 1152;

    const int a_row = l >> 2;           // 0..15 (+16i)
    const int a_c   = (l & 3) << 2;     // k-offset 0,4,8,12
    const int b_kk  = l >> 3;           // 0..7 (+8i)
    const int b_c   = (l & 7) << 2;     // n-offset 0..28
    const int mt    = (l >> 3) << 3;    // 0..56
    const int nt    = (l & 7) << 2;     // 0..28

    float4 sa[4], sb[2];
    auto load_step = [&](int s) {
        const int k0 = kbase + s * 16;
        #pragma unroll
        for (int i = 0; i < 4; ++i)
            sa[i] = *reinterpret_cast<const float4*>(
                Amat + (size_t)(r0 + a_row + 16 * i) * F2 + k0 + a_c);
        #pragma unroll
        for (int i = 0; i < 2; ++i)
            sb[i] = *reinterpret_cast<const float4*>(
                Bmat + (size_t)(k0 + b_kk + 8 * i) * Hh + n0 + b_c);
    };
    auto write_step = [&](int buf) {
        #pragma unroll
        for (int i = 0; i < 4; ++i) {
            const int row = a_row + 16 * i;
            float* dst = As_w + buf * 1088;
            dst[(a_c + 0) * 68 + row] = sa[i].x;
            dst[(a_c + 1) * 68 + row] = sa[i].y;
            dst[(a_c + 2) * 68 + row] = sa[i].z;
            dst[(a_c + 3) * 68 + row] = sa[i].w;
        }
        #pragma unroll
        for (int i = 0; i < 2; ++i)
            *reinterpret_cast<float4*>(
                &Bs_w[buf * 576 + (b_kk + 8 * i) * 36 + b_c]) = sb[i];
    };

    float acc[8][4];
    #pragma unroll
    for (int i = 0; i < 8; ++i)
        #pragma unroll
        for (int j = 0; j < 4; ++j) acc[i][j] = 0.f;

    auto compute = [&](int buf) {
        #pragma unroll
        for (int kk = 0; kk < 16; ++kk) {
            const float* ar = As_w + buf * 1088 + kk * 68 + mt;
            float4 a0 = *reinterpret_cast<const float4*>(ar);
            float4 a1 = *reinterpret_cast<const float4*>(ar + 4);
            float4 b  = *reinterpret_cast<const float4*>(
                Bs_w + buf * 576 + kk * 36 + nt);
            float av[8] = {a0.x, a0.y, a0.z, a0.w, a1.x, a1.y, a1.z, a1.w};
            float bv[4] = {b.x, b.y, b.z, b.w};
            #pragma unroll
            for (int i = 0; i < 8; ++i)
                #pragma unroll
                for (int j = 0; j < 4; ++j)
                    acc[i][j] = fmaf(av[i], bv[j], acc[i][j]);
        }
    };

    // barrier-free pipelined main loop (per-wave private staging)
    load_step(0);
    write_step(0);
    load_step(1);
    #pragma unroll 1
    for (int s = 0; s < 8; ++s) {
        const int cur = s & 1;
        compute(cur);
        if (s + 1 < 8) {
            write_step(cur ^ 1);          // regs hold tile s+1
            if (s + 2 < 8) load_step(s + 2);
        }
    }

    // ---- epilogue: 8-way cross-wave reduction through reused LDS ----
    __syncthreads();                      // all waves done with staging reads
    float* red = smem;                    // 8 * 2304 floats, lane-stride 36
    #pragma unroll
    for (int i8 = 0; i8 < 8; ++i8)
        *reinterpret_cast<float4*>(&red[w * 2304 + l * 36 + 4 * i8]) =
            make_float4(acc[i8][0], acc[i8][1], acc[i8][2], acc[i8][3]);
    __syncthreads();
    {
        // wave w finalizes outputs o in [w*256, w*256+256); lane l -> o = w*256+4l..+3
        const int l_orig = w * 8 + (l >> 3);
        const int off = l_orig * 36 + 4 * (l & 7);
        float4 o = make_float4(0.f, 0.f, 0.f, 0.f);
        #pragma unroll
        for (int p = 0; p < 8; ++p) {
            float4 v = *reinterpret_cast<const float4*>(&red[p * 2304 + off]);
            o.x += v.x; o.y += v.y; o.z += v.z; o.w += v.w;
        }
        const int m = w * 8 + (l & 7);
        const int n = (l >> 3) << 2;
        *reinterpret_cast<float4*>(Out + (size_t)(r0 + m) * Hh + n0 + n) = o;
    }
}

// ---------------- K2: combine (R11, validated): logits = w2.relu(T+V+b1)+b2 ----
__global__ __launch_bounds__(256) void combine_kernel(
    const float* __restrict__ Tfin, const float* __restrict__ Vfin,
    const float* __restrict__ b1, const float* __restrict__ w2,
    const float* __restrict__ b2, float* __restrict__ logits)
{
    const int bid = blockIdx.x;
    const int b  = bid >> 6;
    const int sc = (bid >> 3) & 7;
    const int rq = bid & 7;
    const int t = threadIdx.x;
    const int wave = t >> 6, lane = t & 63;
    __shared__ float Vs[8][516];
    {
        const int row = t >> 5;
        const int f0  = t & 31;
        const float* src = Vfin + (size_t)(b * Ss + sc * 8 + row) * Hh;
        #pragma unroll
        for (int j = 0; j < 4; ++j)
            *reinterpret_cast<float4*>(&Vs[row][(f0 + 32 * j) * 4]) =
                *reinterpret_cast<const float4*>(src + (f0 + 32 * j) * 4);
    }
    float w2r[8], b1r[8];
    #pragma unroll
    for (int j = 0; j < 8; ++j) { w2r[j] = w2[lane + 64 * j]; b1r[j] = b1[lane + 64 * j]; }
    const float bias2 = b2[0];
    float tj0[8], tj1[8];
    {
        const int r0i = b * 64 + rq * 8 + wave * 2;
        const float* t0 = Tfin + (size_t)r0i * Hh;
        const float* t1 = t0 + Hh;
        #pragma unroll
        for (int j = 0; j < 8; ++j) {
            tj0[j] = t0[lane + 64 * j] + b1r[j];
            tj1[j] = t1[lane + 64 * j] + b1r[j];
        }
    }
    __syncthreads();
    const int rbase = b * 64 + rq * 8 + wave * 2;
    #pragma unroll
    for (int si = 0; si < 8; ++si) {
        float s0 = 0.f, s1 = 0.f;
        #pragma unroll
        for (int j = 0; j < 8; ++j) {
            const float v = Vs[si][lane + 64 * j];
            s0 = fmaf(fmaxf(tj0[j] + v, 0.f), w2r[j], s0);
            s1 = fmaf(fmaxf(tj1[j] + v, 0.f), w2r[j], s1);
        }
        s0 = wave_scan_add(s0);
        s1 = wave_scan_add(s1);
        if (lane == 63) {
            logits[(size_t)rbase * Ss + sc * 8 + si]       = s0 + bias2;
            logits[(size_t)(rbase + 1) * Ss + sc * 8 + si] = s1 + bias2;
        }
    }
}

// ---------------- K3: DP via DPP prefix-max (validated) ----------------
__global__ __launch_bounds__(256) void dp_kernel(
    const float* __restrict__ logits, const float* __restrict__ labels,
    float* __restrict__ out)
{
    const int b = blockIdx.x;
    const int t = threadIdx.x;
    const int k = t >> 6, rl = t & 63;
    const int sI = 63 - rl;
    __shared__ float lgs[Kc][Nn][Ss];
    __shared__ unsigned long long ch[Kc][Nn];
    __shared__ float bestS[Kc], aggS[Kc];
    __shared__ int alS[Kc][Nn];
    const float* lg = logits + (size_t)((b * Kc + k) * Nn) * Ss;
    float lv[Nn];
    #pragma unroll
    for (int n = 0; n < Nn; ++n) {
        lv[n] = lg[n * Ss + sI];
        lgs[k][n][sI] = lv[n];
    }
    float arr = -100.0f;
    #pragma unroll
    for (int n = Nn - 1; n >= 0; --n) {
        const float L = logsigf(lv[n]);
        const float c = (n == Nn - 1) ? L : (L + arr);
        const bool in_band = (rl <= 63 - n) && (rl >= 15 - n);   // s in [n, 48+n]
        float m = in_band ? c : -INFINITY;
        m = wave_scan_max(m);
        const float row = in_band ? fmaxf(m, -100.0f) : -100.0f;
        float rnA = __int_as_float(__builtin_amdgcn_update_dpp(
            __float_as_int(-1e30f), __float_as_int(row), 0x111, 0xf, 0xf, false));
        float b15 = __int_as_float(__builtin_amdgcn_update_dpp(
            0, __float_as_int(row), 0x142, 0xa, 0xf, false));
        float b31 = __int_as_float(__builtin_amdgcn_update_dpp(
            0, __float_as_int(row), 0x143, 0xc, 0xf, false));
        float rn = ((rl & 15) == 0 && rl != 0) ? ((rl == 32) ? b31 : b15) : rnA;
        unsigned long long mask = __ballot(in_band && (c >= rn));
        if (rl == 0) ch[k][n] = __brevll(mask);
        arr = row;
    }
    const float best = __shfl(arr, 63);
    __syncthreads();
    if (rl == 0) {
        float agg = 0.f;
        int start = 0;
        bool dead = false;
        int alignv[Nn];
        #pragma unroll
        for (int n = 0; n < Nn; ++n) {
            unsigned long long m2 = dead ? 0ull : (ch[k][n] & (~0ull << start));
            if (m2) {
                const int s = __builtin_ctzll(m2);
                agg += lgs[k][n][s];
                alignv[n] = s;
                start = s + 1;
            } else {
                alignv[n] = 0;
                dead = true;
            }
        }
        bestS[k] = best; aggS[k] = agg;
        #pragma unroll
        for (int n = 0; n < Nn; ++n) alS[k][n] = alignv[n];
    }
    __syncthreads();
    if (t == 0) {
        int kb = 0; float bb = bestS[0];
        #pragma unroll
        for (int kk = 1; kk < Kc; ++kk)
            if (bestS[kk] > bb) { bb = bestS[kk]; kb = kk; }
        out[b] = 1.0f / (1.0f + expf(-aggS[kb]));
        out[Bsz + b] = labels[b];
        #pragma unroll
        for (int n = 0; n < Nn; ++n)
            out[2 * Bsz + b * Nn + n] = (float)alS[kb][n];
    }
}

extern "C" void kernel_launch(void* const* d_in, const int* in_sizes, int n_in,
                              void* d_out, int out_size, void* d_ws, size_t ws_size,
                              hipStream_t stream) {
    const float* seg    = (const float*)d_in[0];
    const float* vid    = (const float*)d_in[1];
    const float* labels = (const float*)d_in[2];
    const float* W1     = (const float*)d_in[3];
    const float* b1     = (const float*)d_in[4];
    const float* w2     = (const float*)d_in[5];
    const float* b2     = (const float*)d_in[6];
    float* out = (float*)d_out;

    float* Tfin   = (float*)d_ws;
    float* Vfin   = Tfin + (size_t)512 * Hh;
    float* logits = Vfin + (size_t)512 * Hh;

    hipLaunchKernelGGL(gemm_kernel, dim3(256), dim3(512), 0, stream,
                       seg, vid, W1, Tfin, Vfin);
    hipLaunchKernelGGL(combine_kernel, dim3(512), dim3(256), 0, stream,
                       Tfin, Vfin, b1, w2, b2, logits);
    hipLaunchKernelGGL(dp_kernel, dim3(Bsz), dim3(256), 0, stream, logits, labels, out);
}

// Round 13
// 49.523 us; speedup vs baseline: 1.9951x; 1.0690x over previous
//
#include <hip/hip_runtime.h>
#include <math.h>

#define Bsz 8
#define Kc 4
#define Nn 16
#define Ss 64
#define Hh 512
#define F2 1024   // 2H = per-part K dim

__device__ __forceinline__ float logsigf(float x) {
    return fminf(x, 0.0f) - log1pf(expf(-fabsf(x)));
}

// ---- DPP wave64 inclusive scans ----
template<int Ctrl, int RowMask>
__device__ __forceinline__ float dpp_add(float x) {
    int v = __builtin_amdgcn_update_dpp(0, __float_as_int(x), Ctrl, RowMask, 0xf, false);
    return x + __int_as_float(v);
}
template<int Ctrl, int RowMask>
__device__ __forceinline__ float dpp_max(float x) {
    int v = __builtin_amdgcn_update_dpp(__float_as_int(-INFINITY), __float_as_int(x),
                                        Ctrl, RowMask, 0xf, false);
    return fmaxf(x, __int_as_float(v));
}
__device__ __forceinline__ float wave_scan_add(float x) {
    x = dpp_add<0x111, 0xf>(x); x = dpp_add<0x112, 0xf>(x);
    x = dpp_add<0x114, 0xf>(x); x = dpp_add<0x118, 0xf>(x);
    x = dpp_add<0x142, 0xa>(x); x = dpp_add<0x143, 0xc>(x);
    return x;
}
__device__ __forceinline__ float wave_scan_max(float x) {
    x = dpp_max<0x111, 0xf>(x); x = dpp_max<0x112, 0xf>(x);
    x = dpp_max<0x114, 0xf>(x); x = dpp_max<0x118, 0xf>(x);
    x = dpp_max<0x142, 0xa>(x); x = dpp_max<0x143, 0xc>(x);
    return x;
}

// ---------------- K1: GEMM — XCD-clustered, A in registers, B-only LDS ----------
// grid 256 (1-D).  xcd = lin&7: z = xcd>>2, xx = (xcd&3)*2+(idx&1), yy = idx>>1
// (per-XCD working set 2.5 MB < 4 MB L2 — verified R12: FETCH 87->12 MB).
// 512 thr = 8 waves; wave w owns K[w*128, w*128+128).
// B: private per-wave LDS, BK=16 double-buffered (broadcast b128 reads, conflict-free).
// A: DIRECT global->register, per-4k-quad double-buffered in two NAMED reg arrays
//    (static indexing only).  Lanes sharing mt read identical addrs -> coalesced merge.
// No __syncthreads in the main loop.  8m x 4n microtile.  Epilogue: R12 (validated).
__global__ __launch_bounds__(512) void gemm_kernel(
    const float* __restrict__ seg, const float* __restrict__ vid,
    const float* __restrict__ W1,
    float* __restrict__ Tfin, float* __restrict__ Vfin)
{
    const int lin = blockIdx.x;
    const int xcd = lin & 7;
    const int idx = lin >> 3;
    const int z   = xcd >> 2;
    const int xx  = (xcd & 3) * 2 + (idx & 1);
    const int yy  = idx >> 1;
    const float* __restrict__ Amat = z ? vid : seg;
    const float* __restrict__ Bmat = W1 + (z ? (size_t)F2 * Hh : 0);
    float* __restrict__ Out = z ? Vfin : Tfin;
    const int r0 = xx * 64;
    const int n0 = yy * 32;

    const int t = threadIdx.x;
    const int w = t >> 6;
    const int l = t & 63;
    const int kbase = w << 7;           // w*128

    __shared__ __align__(16) float smem[18432];   // B staging (9216) U epilogue red (18432)
    float* Bs_w = smem + w * 1152;      // [2 buf][16 kk][36]

    const int b_kk = l >> 3;            // 0..7 (+8)
    const int b_c  = (l & 7) << 2;      // 0..28
    const int mt   = (l >> 3) << 3;     // 0..56
    const int nt   = (l & 7) << 2;      // 0..28

    // 8 per-lane A row pointers (k-quad offset q fits the 13-bit imm: q*16B <= 496B)
    const float* pR[8];
    #pragma unroll
    for (int i = 0; i < 8; ++i)
        pR[i] = Amat + (size_t)(r0 + mt + i) * F2 + kbase;

    float4 bA, bB;
    auto loadB = [&](int s) {
        const int k0 = kbase + s * 16;
        bA = *reinterpret_cast<const float4*>(Bmat + (size_t)(k0 + b_kk) * Hh + n0 + b_c);
        bB = *reinterpret_cast<const float4*>(Bmat + (size_t)(k0 + b_kk + 8) * Hh + n0 + b_c);
    };
    auto writeB = [&](int buf) {
        *reinterpret_cast<float4*>(&Bs_w[buf * 576 + b_kk * 36 + b_c]) = bA;
        *reinterpret_cast<float4*>(&Bs_w[buf * 576 + (b_kk + 8) * 36 + b_c]) = bB;
    };

    float4 aP[8], aQ[8];                 // two named A quad buffers (static indexing)
    auto loadA_P = [&](int q) {
        #pragma unroll
        for (int i = 0; i < 8; ++i)
            aP[i] = *reinterpret_cast<const float4*>(pR[i] + q * 4);
    };
    auto loadA_Q = [&](int q) {
        #pragma unroll
        for (int i = 0; i < 8; ++i)
            aQ[i] = *reinterpret_cast<const float4*>(pR[i] + q * 4);
    };

    float acc[8][4];
    #pragma unroll
    for (int i = 0; i < 8; ++i)
        #pragma unroll
        for (int j = 0; j < 4; ++j) acc[i][j] = 0.f;

    // compute one 4-k quad from reg array A4 against B LDS buffer `buf`, local quad qq
    auto quadP = [&](int buf, int qq) {
        #pragma unroll
        for (int j = 0; j < 4; ++j) {
            float4 b = *reinterpret_cast<const float4*>(
                &Bs_w[buf * 576 + (qq * 4 + j) * 36 + nt]);
            float bv[4] = {b.x, b.y, b.z, b.w};
            #pragma unroll
            for (int i = 0; i < 8; ++i) {
                const float a = j == 0 ? aP[i].x : j == 1 ? aP[i].y : j == 2 ? aP[i].z : aP[i].w;
                #pragma unroll
                for (int jj = 0; jj < 4; ++jj)
                    acc[i][jj] = fmaf(a, bv[jj], acc[i][jj]);
            }
        }
    };
    auto quadQ = [&](int buf, int qq) {
        #pragma unroll
        for (int j = 0; j < 4; ++j) {
            float4 b = *reinterpret_cast<const float4*>(
                &Bs_w[buf * 576 + (qq * 4 + j) * 36 + nt]);
            float bv[4] = {b.x, b.y, b.z, b.w};
            #pragma unroll
            for (int i = 0; i < 8; ++i) {
                const float a = j == 0 ? aQ[i].x : j == 1 ? aQ[i].y : j == 2 ? aQ[i].z : aQ[i].w;
                #pragma unroll
                for (int jj = 0; jj < 4; ++jj)
                    acc[i][jj] = fmaf(a, bv[jj], acc[i][jj]);
            }
        }
    };

    loadB(0); writeB(0); loadB(1);
    loadA_P(0);
    #pragma unroll 1
    for (int s = 0; s < 8; ++s) {
        const int cur = s & 1;
        #pragma unroll
        for (int qq = 0; qq < 4; ++qq) {
            const int q = s * 4 + qq;
            if ((qq & 1) == 0) {
                if (q + 1 < 32) loadA_Q(q + 1);    // prefetch next quad
                quadP(cur, qq);
            } else {
                if (q + 1 < 32) loadA_P(q + 1);
                quadQ(cur, qq);
            }
        }
        if (s + 1 < 8) {
            writeB(cur ^ 1);                        // regs hold B tile s+1
            if (s + 2 < 8) loadB(s + 2);
        }
    }

    // ---- epilogue: 8-way cross-wave reduction through reused LDS (R12, validated) ----
    __syncthreads();
    float* red = smem;
    #pragma unroll
    for (int i8 = 0; i8 < 8; ++i8)
        *reinterpret_cast<float4*>(&red[w * 2304 + l * 36 + 4 * i8]) =
            make_float4(acc[i8][0], acc[i8][1], acc[i8][2], acc[i8][3]);
    __syncthreads();
    {
        const int l_orig = w * 8 + (l >> 3);
        const int off = l_orig * 36 + 4 * (l & 7);
        float4 o = make_float4(0.f, 0.f, 0.f, 0.f);
        #pragma unroll
        for (int p = 0; p < 8; ++p) {
            float4 v = *reinterpret_cast<const float4*>(&red[p * 2304 + off]);
            o.x += v.x; o.y += v.y; o.z += v.z; o.w += v.w;
        }
        const int m = w * 8 + (l & 7);
        const int n = (l >> 3) << 2;
        *reinterpret_cast<float4*>(Out + (size_t)(r0 + m) * Hh + n0 + n) = o;
    }
}

// ---------------- K2: combine (validated): logits = w2.relu(T+V+b1)+b2 ----
__global__ __launch_bounds__(256) void combine_kernel(
    const float* __restrict__ Tfin, const float* __restrict__ Vfin,
    const float* __restrict__ b1, const float* __restrict__ w2,
    const float* __restrict__ b2, float* __restrict__ logits)
{
    const int bid = blockIdx.x;
    const int b  = bid >> 6;
    const int sc = (bid >> 3) & 7;
    const int rq = bid & 7;
    const int t = threadIdx.x;
    const int wave = t >> 6, lane = t & 63;
    __shared__ float Vs[8][516];
    {
        const int row = t >> 5;
        const int f0  = t & 31;
        const float* src = Vfin + (size_t)(b * Ss + sc * 8 + row) * Hh;
        #pragma unroll
        for (int j = 0; j < 4; ++j)
            *reinterpret_cast<float4*>(&Vs[row][(f0 + 32 * j) * 4]) =
                *reinterpret_cast<const float4*>(src + (f0 + 32 * j) * 4);
    }
    float w2r[8], b1r[8];
    #pragma unroll
    for (int j = 0; j < 8; ++j) { w2r[j] = w2[lane + 64 * j]; b1r[j] = b1[lane + 64 * j]; }
    const float bias2 = b2[0];
    float tj0[8], tj1[8];
    {
        const int r0i = b * 64 + rq * 8 + wave * 2;
        const float* t0 = Tfin + (size_t)r0i * Hh;
        const float* t1 = t0 + Hh;
        #pragma unroll
        for (int j = 0; j < 8; ++j) {
            tj0[j] = t0[lane + 64 * j] + b1r[j];
            tj1[j] = t1[lane + 64 * j] + b1r[j];
        }
    }
    __syncthreads();
    const int rbase = b * 64 + rq * 8 + wave * 2;
    #pragma unroll
    for (int si = 0; si < 8; ++si) {
        float s0 = 0.f, s1 = 0.f;
        #pragma unroll
        for (int j = 0; j < 8; ++j) {
            const float v = Vs[si][lane + 64 * j];
            s0 = fmaf(fmaxf(tj0[j] + v, 0.f), w2r[j], s0);
            s1 = fmaf(fmaxf(tj1[j] + v, 0.f), w2r[j], s1);
        }
        s0 = wave_scan_add(s0);
        s1 = wave_scan_add(s1);
        if (lane == 63) {
            logits[(size_t)rbase * Ss + sc * 8 + si]       = s0 + bias2;
            logits[(size_t)(rbase + 1) * Ss + sc * 8 + si] = s1 + bias2;
        }
    }
}

// ---------------- K3: DP via DPP prefix-max (validated) ----------------
__global__ __launch_bounds__(256) void dp_kernel(
    const float* __restrict__ logits, const float* __restrict__ labels,
    float* __restrict__ out)
{
    const int b = blockIdx.x;
    const int t = threadIdx.x;
    const int k = t >> 6, rl = t & 63;
    const int sI = 63 - rl;
    __shared__ float lgs[Kc][Nn][Ss];
    __shared__ unsigned long long ch[Kc][Nn];
    __shared__ float bestS[Kc], aggS[Kc];
    __shared__ int alS[Kc][Nn];
    const float* lg = logits + (size_t)((b * Kc + k) * Nn) * Ss;
    float lv[Nn];
    #pragma unroll
    for (int n = 0; n < Nn; ++n) {
        lv[n] = lg[n * Ss + sI];
        lgs[k][n][sI] = lv[n];
    }
    float arr = -100.0f;
    #pragma unroll
    for (int n = Nn - 1; n >= 0; --n) {
        const float L = logsigf(lv[n]);
        const float c = (n == Nn - 1) ? L : (L + arr);
        const bool in_band = (rl <= 63 - n) && (rl >= 15 - n);   // s in [n, 48+n]
        float m = in_band ? c : -INFINITY;
        m = wave_scan_max(m);
        const float row = in_band ? fmaxf(m, -100.0f) : -100.0f;
        float rnA = __int_as_float(__builtin_amdgcn_update_dpp(
            __float_as_int(-1e30f), __float_as_int(row), 0x111, 0xf, 0xf, false));
        float b15 = __int_as_float(__builtin_amdgcn_update_dpp(
            0, __float_as_int(row), 0x142, 0xa, 0xf, false));
        float b31 = __int_as_float(__builtin_amdgcn_update_dpp(
            0, __float_as_int(row), 0x143, 0xc, 0xf, false));
        float rn = ((rl & 15) == 0 && rl != 0) ? ((rl == 32) ? b31 : b15) : rnA;
        unsigned long long mask = __ballot(in_band && (c >= rn));
        if (rl == 0) ch[k][n] = __brevll(mask);
        arr = row;
    }
    const float best = __shfl(arr, 63);
    __syncthreads();
    if (rl == 0) {
        float agg = 0.f;
        int start = 0;
        bool dead = false;
        int alignv[Nn];
        #pragma unroll
        for (int n = 0; n < Nn; ++n) {
            unsigned long long m2 = dead ? 0ull : (ch[k][n] & (~0ull << start));
            if (m2) {
                const int s = __builtin_ctzll(m2);
                agg += lgs[k][n][s];
                alignv[n] = s;
                start = s + 1;
            } else {
                alignv[n] = 0;
                dead = true;
            }
        }
        bestS[k] = best; aggS[k] = agg;
        #pragma unroll
        for (int n = 0; n < Nn; ++n) alS[k][n] = alignv[n];
    }
    __syncthreads();
    if (t == 0) {
        int kb = 0; float bb = bestS[0];
        #pragma unroll
        for (int kk = 1; kk < Kc; ++kk)
            if (bestS[kk] > bb) { bb = bestS[kk]; kb = kk; }
        out[b] = 1.0f / (1.0f + expf(-aggS[kb]));
        out[Bsz + b] = labels[b];
        #pragma unroll
        for (int n = 0; n < Nn; ++n)
            out[2 * Bsz + b * Nn + n] = (float)alS[kb][n];
    }
}

extern "C" void kernel_launch(void* const* d_in, const int* in_sizes, int n_in,
                              void* d_out, int out_size, void* d_ws, size_t ws_size,
                              hipStream_t stream) {
    const float* seg    = (const float*)d_in[0];
    const float* vid    = (const float*)d_in[1];
    const float* labels = (const float*)d_in[2];
    const float* W1     = (const float*)d_in[3];
    const float* b1     = (const float*)d_in[4];
    const float* w2     = (const float*)d_in[5];
    const float* b2     = (const float*)d_in[6];
    float* out = (float*)d_out;

    float* Tfin   = (float*)d_ws;
    float* Vfin   = Tfin + (size_t)512 * Hh;
    float* logits = Vfin + (size_t)512 * Hh;

    hipLaunchKernelGGL(gemm_kernel, dim3(256), dim3(512), 0, stream,
                       seg, vid, W1, Tfin, Vfin);
    hipLaunchKernelGGL(combine_kernel, dim3(512), dim3(256), 0, stream,
                       Tfin, Vfin, b1, w2, b2, logits);
    hipLaunchKernelGGL(dp_kernel, dim3(Bsz), dim3(256), 0, stream, logits, labels, out);
}